// Round 6
// baseline (120.084 us; speedup 1.0000x reference)
//
#include <hip/hip_runtime.h>
#include <hip/hip_bf16.h>

#define BB 8
#define CC 64
#define NNN 4096
#define KK 20
#define MM 8
#define OC 64
#define CM 512

typedef __attribute__((ext_vector_type(8))) short bf16x8;
typedef __attribute__((ext_vector_type(4))) float f32x4;
typedef __attribute__((ext_vector_type(2))) float f32x2;

__device__ __forceinline__ unsigned short f2bf(float f) {
    union { float f; unsigned int u; } v; v.f = f;
    unsigned int u = v.u;
    return (unsigned short)((u + 0x7FFFu + ((u >> 16) & 1u)) >> 16);
}
__device__ __forceinline__ unsigned int pack2bf(float a, float b) {
    union { __hip_bfloat162 h; unsigned int u; } pk;
    pk.h = __float22bfloat162_rn(make_float2(a, b));
    return pk.u;
}
__device__ __forceinline__ float bfhi2f(unsigned int u) {
    union { unsigned int u; float f; } v; v.u = u & 0xffff0000u; return v.f;
}
__device__ __forceinline__ float bflo2f(unsigned int u) {
    union { unsigned int u; float f; } v; v.u = u << 16; return v.f;
}

// ---------------------------------------------------------------------------
// prep: blk<512  : transpose feature (B,C,N) -> ftr bf16 (B,N,C)
//       512..515 : Wb = bf16 conv_w with permuted cols  col = (c&7)*64+(c>>3)*8+m
//       516..547 : proj[b][n][m] = sum_c x[b][c][n] * kern[c][m]
// ---------------------------------------------------------------------------
__global__ __launch_bounds__(256) void prep_kernel(const float* __restrict__ x,
                                                   const float* __restrict__ feature,
                                                   const float* __restrict__ kern,
                                                   const float* __restrict__ conv_w,
                                                   unsigned short* __restrict__ ftr,
                                                   unsigned short* __restrict__ Wb,
                                                   float* __restrict__ proj) {
    int blk = blockIdx.x;
    int t = threadIdx.x;
    if (blk < 512) {
        __shared__ float tile[64 * 65];
        int b = blk & 7;
        int n0 = (blk >> 3) << 6;
        const float* fb = feature + b * (CC * NNN);
        #pragma unroll
        for (int s = 0; s < 16; ++s) {
            int i = t + s * 256;
            int c = i >> 6, nn = i & 63;
            tile[c * 65 + nn] = fb[c * NNN + n0 + nn];
        }
        __syncthreads();
        unsigned short* fo = ftr + b * (NNN * CC) + n0 * CC;
        #pragma unroll
        for (int s = 0; s < 16; ++s) {
            int i = t + s * 256;
            int n = i >> 6, cc = i & 63;
            fo[n * CC + cc] = f2bf(tile[cc * 65 + n]);
        }
    } else if (blk < 516) {
        int base = (blk - 512) * 8192;
        #pragma unroll
        for (int s = 0; s < 32; ++s) {
            int i = base + t + s * 256;          // i = o*512 + col
            int o = i >> 9, col = i & 511;
            int j = col >> 6, cL = (col >> 3) & 7, m = col & 7;
            int cm = ((cL * 8 + j) << 3) | m;
            Wb[i] = f2bf(conv_w[(o << 9) | cm]);
        }
    } else {
        int pb = blk - 516;                      // 0..31
        int b = pb >> 2;
        int nb = (pb & 3) << 10;
        const float* xb = x + b * (3 * NNN);
        float k0[MM], k1[MM], k2[MM];
        #pragma unroll
        for (int m = 0; m < MM; ++m) {
            k0[m] = kern[m]; k1[m] = kern[MM + m]; k2[m] = kern[2 * MM + m];
        }
        #pragma unroll
        for (int s = 0; s < 4; ++s) {
            int n = nb + s * 256 + t;
            float x0 = xb[n], x1 = xb[NNN + n], x2 = xb[2 * NNN + n];
            float pr[MM];
            #pragma unroll
            for (int m = 0; m < MM; ++m)
                pr[m] = x0 * k0[m] + x1 * k1[m] + x2 * k2[m];
            float* pp = proj + ((size_t)b * NNN + n) * MM;
            *(float4*)pp = make_float4(pr[0], pr[1], pr[2], pr[3]);
            *(float4*)(pp + 4) = make_float4(pr[4], pr[5], pr[6], pr[7]);
        }
    }
}

// ---------------------------------------------------------------------------
// aggr: barrier-free. 256 thr = 4 independent waves; wave owns 8 points.
// lane = (p = l>>3, h = l&7). h = m for softmax, h = channel-octet for agg.
// perm redistribution is wave-internal via LDS + lgkmcnt only.
// agg[n][col] bf16, col = (c&7)*64 + (c>>3)*8 + m  (coalesced stores).
// ---------------------------------------------------------------------------
__global__ __launch_bounds__(256, 3) void aggr_kernel(const int* __restrict__ nidx,
                                                      const float* __restrict__ proj,
                                                      const unsigned short* __restrict__ ftr,
                                                      unsigned short* __restrict__ agg) {
    __shared__ unsigned short perm[4][8 * 168];   // per-wave: 8 pts x 20k x 8m bf16, stride 168

    int t = threadIdx.x, w = t >> 6, l = t & 63;
    int p = l >> 3, h = l & 7;
    int blk = blockIdx.x;
    int b = blk & 7;                              // XCD-affinity swizzle
    int n0 = ((blk >> 3) << 5) + (w << 3);
    int rowp = b * NNN + n0 + p;                  // this lane-group's global point

    // ---- indices (16B broadcast loads, 80B aligned) ----
    int id[KK];
    {
        const int4* nb4 = (const int4*)(nidx + rowp * KK);
        #pragma unroll
        for (int s = 0; s < 5; ++s) {
            int4 v = nb4[s];
            id[s * 4 + 0] = v.x; id[s * 4 + 1] = v.y;
            id[s * 4 + 2] = v.z; id[s * 4 + 3] = v.w;
        }
    }

    // ---- proj gathers (32B per (p,k), coalesced within octet) ----
    const float* pj = proj + (size_t)b * NNN * MM;
    float pv[KK];
    #pragma unroll
    for (int k = 0; k < KK; ++k) pv[k] = pj[id[k] * MM + h];

    // ---- feature gathers: all 20 in flight (consumed only in k-loop) ----
    const unsigned short* fb = ftr + (size_t)b * NNN * CC;
    uint4 fr[KK];
    #pragma unroll
    for (int k = 0; k < KK; ++k)
        fr[k] = *(const uint4*)(fb + (size_t)id[k] * CC + h * 8);

    // ---- softmax over k (pv[k] -= pv[0]; one_pad at [0, m==0]) ----
    float pbase = pv[0];
    #pragma unroll
    for (int k = 0; k < KK; ++k) pv[k] -= pbase;
    if (h == 0) pv[0] += 1.0f;
    float mx = pv[0];
    #pragma unroll
    for (int k = 1; k < KK; ++k) mx = fmaxf(mx, pv[k]);
    float sum = 0.f;
    #pragma unroll
    for (int k = 0; k < KK; ++k) { pv[k] = __expf(pv[k] - mx); sum += pv[k]; }
    float inv = 1.0f / sum;

    // ---- publish perm (bf16) to wave-local LDS; wave-internal ordering only ----
    {
        unsigned short* pw = perm[w] + p * 168;
        #pragma unroll
        for (int k = 0; k < KK; ++k) pw[k * 8 + h] = f2bf(pv[k] * inv);
    }
    __asm__ __volatile__("s_waitcnt lgkmcnt(0)" ::: "memory");

    // ---- aggregate: acc[c-pair][m] += f[k][c] * perm[k][m] ----
    f32x2 acc[4][MM];
    #pragma unroll
    for (int d = 0; d < 4; ++d)
        #pragma unroll
        for (int m = 0; m < MM; ++m) acc[d][m] = (f32x2){0.f, 0.f};

    const unsigned short* prd = perm[w] + p * 168;
    #pragma unroll
    for (int k = 0; k < KK; ++k) {
        union { bf16x8 v; unsigned int u[4]; } pm8;
        pm8.v = *(const bf16x8*)(prd + k * 8);    // 16B aligned (336p + 16k)
        float pm[MM];
        #pragma unroll
        for (int d = 0; d < 4; ++d) {
            pm[2 * d] = bflo2f(pm8.u[d]);
            pm[2 * d + 1] = bfhi2f(pm8.u[d]);
        }
        const unsigned int* fu = (const unsigned int*)&fr[k];
        f32x2 fv[4];
        #pragma unroll
        for (int d = 0; d < 4; ++d)
            fv[d] = (f32x2){bflo2f(fu[d]), bfhi2f(fu[d])};   // c = h*8+2d, h*8+2d+1
        #pragma unroll
        for (int m = 0; m < MM; ++m) {
            f32x2 pmm = {pm[m], pm[m]};
            #pragma unroll
            for (int d = 0; d < 4; ++d)
                acc[d][m] += fv[d] * pmm;
        }
    }

    // ---- store agg row: chunk jj -> col jj*64 + h*8 + m (128B-coalesced per jj) ----
    unsigned short* ag = agg + (size_t)rowp * CM;
    #pragma unroll
    for (int jj = 0; jj < 8; ++jj) {              // jj = c&7 ; d = jj>>1 ; x/y = parity
        int d = jj >> 1;
        unsigned int d0, d1, d2, d3;
        if ((jj & 1) == 0) {
            d0 = pack2bf(acc[d][0].x, acc[d][1].x);
            d1 = pack2bf(acc[d][2].x, acc[d][3].x);
            d2 = pack2bf(acc[d][4].x, acc[d][5].x);
            d3 = pack2bf(acc[d][6].x, acc[d][7].x);
        } else {
            d0 = pack2bf(acc[d][0].y, acc[d][1].y);
            d1 = pack2bf(acc[d][2].y, acc[d][3].y);
            d2 = pack2bf(acc[d][4].y, acc[d][5].y);
            d3 = pack2bf(acc[d][6].y, acc[d][7].y);
        }
        uint4 vv = make_uint4(d0, d1, d2, d3);
        *(uint4*)(ag + jj * 64 + h * 8) = vv;
    }
}

// ---------------------------------------------------------------------------
// gemm: (32768 x 512) @ (512 x 64) + bias, lrelu, +feature, transposed store.
// 128 thr = 2 waves, each wave: 32 pts x 32 o, no LDS, no barriers.
// ---------------------------------------------------------------------------
__global__ __launch_bounds__(128, 4) void gemm_kernel(const unsigned short* __restrict__ agg,
                                                      const unsigned short* __restrict__ Wb,
                                                      const float* __restrict__ conv_b,
                                                      const float* __restrict__ feature,
                                                      float* __restrict__ out) {
    int t = threadIdx.x, w = t >> 6, l = t & 63;
    int blk = blockIdx.x;
    int b = blk & 7;
    int g = blk >> 3;                 // 0..127
    int Wid = g * 2 + w;              // 0..255
    int og = Wid & 1;
    int pg = Wid >> 1;                // 0..127
    int n0 = pg << 5;
    int oA = og * 32 + (l & 15), oB = oA + 16;
    int q = l >> 4;
    int r0 = b * NNN + n0 + (l & 15);

    const unsigned short* a0p = agg + (size_t)r0 * CM + q * 8;
    const unsigned short* a1p = a0p + 16 * CM;
    const unsigned short* w0p = Wb + (size_t)oA * CM + q * 8;
    const unsigned short* w1p = Wb + (size_t)oB * CM + q * 8;

    // prefetch residual + bias (hide under MFMA loop)
    const float* fA = feature + ((size_t)b * CC + oA) * NNN + n0 + q * 4;
    const float* fB = feature + ((size_t)b * CC + oB) * NNN + n0 + q * 4;
    float4 resA0 = *(const float4*)fA;
    float4 resA1 = *(const float4*)(fA + 16);
    float4 resB0 = *(const float4*)fB;
    float4 resB1 = *(const float4*)(fB + 16);
    float biasA = conv_b[oA], biasB = conv_b[oB];

    f32x4 d00 = {0,0,0,0}, d01 = {0,0,0,0}, d10 = {0,0,0,0}, d11 = {0,0,0,0};
    #pragma unroll
    for (int s = 0; s < 16; ++s) {
        bf16x8 a0 = *(const bf16x8*)(a0p + s * 32);
        bf16x8 a1 = *(const bf16x8*)(a1p + s * 32);
        bf16x8 w0f = *(const bf16x8*)(w0p + s * 32);
        bf16x8 w1f = *(const bf16x8*)(w1p + s * 32);
        d00 = __builtin_amdgcn_mfma_f32_16x16x32_bf16(a0, w0f, d00, 0, 0, 0);
        d01 = __builtin_amdgcn_mfma_f32_16x16x32_bf16(a0, w1f, d01, 0, 0, 0);
        d10 = __builtin_amdgcn_mfma_f32_16x16x32_bf16(a1, w0f, d10, 0, 0, 0);
        d11 = __builtin_amdgcn_mfma_f32_16x16x32_bf16(a1, w1f, d11, 0, 0, 0);
    }

    float* opA = out + ((size_t)b * OC + oA) * NNN + n0 + q * 4;
    float* opB = out + ((size_t)b * OC + oB) * NNN + n0 + q * 4;
    float4 rA0, rA1, rB0, rB1;
    #pragma unroll
    for (int r = 0; r < 4; ++r) {
        float v;
        v = d00[r] + biasA; v = v > 0.f ? v : v * 0.2f; ((float*)&rA0)[r] = v + ((const float*)&resA0)[r];
        v = d10[r] + biasA; v = v > 0.f ? v : v * 0.2f; ((float*)&rA1)[r] = v + ((const float*)&resA1)[r];
        v = d01[r] + biasB; v = v > 0.f ? v : v * 0.2f; ((float*)&rB0)[r] = v + ((const float*)&resB0)[r];
        v = d11[r] + biasB; v = v > 0.f ? v : v * 0.2f; ((float*)&rB1)[r] = v + ((const float*)&resB1)[r];
    }
    *(float4*)opA = rA0;
    *(float4*)(opA + 16) = rA1;
    *(float4*)opB = rB0;
    *(float4*)(opB + 16) = rB1;
}

extern "C" void kernel_launch(void* const* d_in, const int* in_sizes, int n_in,
                              void* d_out, int out_size, void* d_ws, size_t ws_size,
                              hipStream_t stream) {
    const float* x        = (const float*)d_in[0];
    const float* feature  = (const float*)d_in[1];
    const int*   nidx     = (const int*)d_in[2];
    const float* kern     = (const float*)d_in[3];
    const float* conv_w   = (const float*)d_in[4];
    const float* conv_b   = (const float*)d_in[5];
    float* out = (float*)d_out;

    char* ws = (char*)d_ws;
    unsigned short* ftr  = (unsigned short*)ws;                    // 4 MB  (B,N,C) bf16
    unsigned short* Wb   = (unsigned short*)(ws + (4u << 20));     // 64 KB permuted bf16 W
    float*          proj = (float*)(ws + (4u << 20) + (64u << 10)); // 1 MB (B,N,M) f32
    unsigned short* agg  = (unsigned short*)(ws + (5u << 20) + (64u << 10)); // 32 MB

    prep_kernel<<<548, 256, 0, stream>>>(x, feature, kern, conv_w, ftr, Wb, proj);
    aggr_kernel<<<1024, 256, 0, stream>>>(nidx, proj, ftr, agg);
    gemm_kernel<<<1024, 128, 0, stream>>>(agg, Wb, conv_b, feature, out);
}

// Round 8
// 107.031 us; speedup vs baseline: 1.1220x; 1.1220x over previous
//
#include <hip/hip_runtime.h>
#include <hip/hip_bf16.h>

#define BB 8
#define CC 64
#define NNN 4096
#define KK 20
#define MM 8
#define OC 64
#define CM 512
#define PST 168          // perm row stride (u16): conflict-free writes+reads, 16B-aligned rows
#define AST 520          // aggA row stride (u16): 16B-aligned, bank-balanced b128 frags
#define REGW 5504        // per-wave region (u16): 8*168 perm + 8*520 aggA = 1344+4160

typedef __attribute__((ext_vector_type(8))) short bf16x8;
typedef __attribute__((ext_vector_type(4))) float f32x4;
typedef __attribute__((ext_vector_type(2))) float f32x2;

__device__ __forceinline__ unsigned short f2bf(float f) {
    union { float f; unsigned int u; } v; v.f = f;
    unsigned int u = v.u;
    return (unsigned short)((u + 0x7FFFu + ((u >> 16) & 1u)) >> 16);
}
__device__ __forceinline__ unsigned int pack2bf(float a, float b) {
    union { __hip_bfloat162 h; unsigned int u; } pk;
    pk.h = __float22bfloat162_rn(make_float2(a, b));
    return pk.u;
}
__device__ __forceinline__ float bfhi2f(unsigned int u) {
    union { unsigned int u; float f; } v; v.u = u & 0xffff0000u; return v.f;
}
__device__ __forceinline__ float bflo2f(unsigned int u) {
    union { unsigned int u; float f; } v; v.u = u << 16; return v.f;
}

// ---------------------------------------------------------------------------
// prep: blk<512  : transpose feature (B,C,N) -> ftr bf16 (B,N,C)
//       512..515 : Wb = bf16 conv_w (natural [o][c*8+m] layout)
//       516..547 : proj[b][n][m] = sum_c x[b][c][n] * kern[c][m]
// ---------------------------------------------------------------------------
__global__ __launch_bounds__(256) void prep_kernel(const float* __restrict__ x,
                                                   const float* __restrict__ feature,
                                                   const float* __restrict__ kern,
                                                   const float* __restrict__ conv_w,
                                                   unsigned short* __restrict__ ftr,
                                                   unsigned short* __restrict__ Wb,
                                                   float* __restrict__ proj) {
    int blk = blockIdx.x;
    int t = threadIdx.x;
    if (blk < 512) {
        __shared__ float tile[64 * 65];
        int b = blk & 7;
        int n0 = (blk >> 3) << 6;
        const float* fb = feature + b * (CC * NNN);
        #pragma unroll
        for (int s = 0; s < 16; ++s) {
            int i = t + s * 256;
            int c = i >> 6, nn = i & 63;
            tile[c * 65 + nn] = fb[c * NNN + n0 + nn];
        }
        __syncthreads();
        unsigned short* fo = ftr + b * (NNN * CC) + n0 * CC;
        #pragma unroll
        for (int s = 0; s < 16; ++s) {
            int i = t + s * 256;
            int n = i >> 6, cc = i & 63;
            fo[n * CC + cc] = f2bf(tile[cc * 65 + n]);
        }
    } else if (blk < 516) {
        int base = (blk - 512) * 8192;
        #pragma unroll
        for (int s = 0; s < 32; ++s) {
            int i = base + t + s * 256;
            Wb[i] = f2bf(conv_w[i]);
        }
    } else {
        int pb = blk - 516;                      // 0..31
        int b = pb >> 2;
        int nb = (pb & 3) << 10;
        const float* xb = x + b * (3 * NNN);
        float k0[MM], k1[MM], k2[MM];
        #pragma unroll
        for (int m = 0; m < MM; ++m) {
            k0[m] = kern[m]; k1[m] = kern[MM + m]; k2[m] = kern[2 * MM + m];
        }
        #pragma unroll
        for (int s = 0; s < 4; ++s) {
            int n = nb + s * 256 + t;
            float x0 = xb[n], x1 = xb[NNN + n], x2 = xb[2 * NNN + n];
            float pr[MM];
            #pragma unroll
            for (int m = 0; m < MM; ++m)
                pr[m] = x0 * k0[m] + x1 * k1[m] + x2 * k2[m];
            float* pp = proj + ((size_t)b * NNN + n) * MM;
            *(float4*)pp = make_float4(pr[0], pr[1], pr[2], pr[3]);
            *(float4*)(pp + 4) = make_float4(pr[4], pr[5], pr[6], pr[7]);
        }
    }
}

// ---------------------------------------------------------------------------
// main: 16 pts/block, 128 thr = 2 waves; wave owns 8 points end-to-end
// (ids -> proj+ftr gathers -> softmax -> wave-local perm -> agg -> own aggA
//  region). ONE __syncthreads, then 16x16x32 MFMA + fused epilogue.
// Gather pipeline: preload chunk 0; prefetch chunk c4+1 inside loop (R5 scheme).
// ---------------------------------------------------------------------------
__global__ __launch_bounds__(128, 3) void main_kernel(
    const int* __restrict__ nidx,
    const float* __restrict__ proj,
    const unsigned short* __restrict__ ftr,
    const unsigned short* __restrict__ Wb,
    const float* __restrict__ conv_b,
    const float* __restrict__ feature,
    float* __restrict__ out)
{
    __shared__ __align__(16) unsigned short sm[2 * REGW];

    int t = threadIdx.x, w = t >> 6, l = t & 63;
    int p = l >> 3, h = l & 7;                   // point-in-wave, octet lane
    int blk = blockIdx.x;
    int b = blk & 7;                             // XCD-affinity swizzle
    int n0 = (blk >> 3) << 4;
    int rowp = b * NNN + n0 + w * 8 + p;         // lane-group's global point

    unsigned short* permW = sm + w * REGW;            // 8 x PST
    unsigned short* aggW  = sm + w * REGW + 8 * PST;  // 8 x AST

    // ---- ids (5 x int4 broadcast within octet) ----
    int id[KK];
    {
        const int4* nb4 = (const int4*)(nidx + (size_t)rowp * KK);
        #pragma unroll
        for (int s = 0; s < 5; ++s) {
            int4 v = nb4[s];
            id[s * 4 + 0] = v.x; id[s * 4 + 1] = v.y;
            id[s * 4 + 2] = v.z; id[s * 4 + 3] = v.w;
        }
    }

    // ---- proj gathers (softmax inputs) ----
    const float* pj = proj + (size_t)b * NNN * MM;
    float pv[KK];
    #pragma unroll
    for (int k = 0; k < KK; ++k) pv[k] = pj[id[k] * MM + h];

    // ---- ftr gathers: chunk 0 in flight before softmax ----
    const unsigned short* fb = ftr + (size_t)b * NNN * CC;
    uint4 frA[4], frB[4];
    #pragma unroll
    for (int j = 0; j < 4; ++j)
        frA[j] = *(const uint4*)(fb + (size_t)id[j] * CC + h * 8);

    // ---- softmax over k (shift-invariant; one_pad at [0, m==0]) ----
    if (h == 0) pv[0] += 1.0f;
    float mx = pv[0];
    #pragma unroll
    for (int k = 1; k < KK; ++k) mx = fmaxf(mx, pv[k]);
    float sum = 0.f;
    #pragma unroll
    for (int k = 0; k < KK; ++k) { pv[k] = __expf(pv[k] - mx); sum += pv[k]; }
    float inv = 1.0f / sum;

    // ---- publish perm bf16 to wave-local LDS (conflict-free stride 168) ----
    {
        unsigned short* pw = permW + p * PST;
        #pragma unroll
        for (int k = 0; k < KK; ++k) pw[k * 8 + h] = f2bf(pv[k] * inv);
    }
    __asm__ __volatile__("s_waitcnt lgkmcnt(0)" ::: "memory");

    // ---- aggregate: acc[c-pair][m] += f[k][c] * perm[k][m] ----
    // double-buffer: consume cur (chunk c4), prefetch chunk c4+1 into nxt.
    f32x2 acc[4][MM];
    #pragma unroll
    for (int d = 0; d < 4; ++d)
        #pragma unroll
        for (int m = 0; m < MM; ++m) acc[d][m] = (f32x2){0.f, 0.f};

    const unsigned short* prd = permW + p * PST;
    #pragma unroll
    for (int c4 = 0; c4 < 5; ++c4) {
        uint4* cur = (c4 & 1) ? frB : frA;
        uint4* nxt = (c4 & 1) ? frA : frB;
        if (c4 < 4) {
            #pragma unroll
            for (int j = 0; j < 4; ++j)
                nxt[j] = *(const uint4*)(fb + (size_t)id[(c4 + 1) * 4 + j] * CC + h * 8);
        }
        #pragma unroll
        for (int j = 0; j < 4; ++j) {
            int k = c4 * 4 + j;
            union { bf16x8 v; unsigned int u[4]; } pm8;
            pm8.v = *(const bf16x8*)(prd + k * 8);
            float pm[MM];
            #pragma unroll
            for (int d = 0; d < 4; ++d) {
                pm[2 * d] = bflo2f(pm8.u[d]);
                pm[2 * d + 1] = bfhi2f(pm8.u[d]);
            }
            const unsigned int* fu = (const unsigned int*)&cur[j];
            f32x2 fv[4];
            #pragma unroll
            for (int d = 0; d < 4; ++d)
                fv[d] = (f32x2){bflo2f(fu[d]), bfhi2f(fu[d])};
            #pragma unroll
            for (int m = 0; m < MM; ++m) {
                f32x2 pmm = {pm[m], pm[m]};
                #pragma unroll
                for (int d = 0; d < 4; ++d)
                    acc[d][m] += fv[d] * pmm;
            }
        }
    }

    // ---- pack to own aggA region: row p, col-order c*8+m (bank-balanced) ----
    {
        unsigned short* ag = aggW + p * AST;
        #pragma unroll
        for (int i = 0; i < 8; ++i) {            // c = h*8 + i
            int d = i >> 1;
            unsigned int d0, d1, d2, d3;
            if ((i & 1) == 0) {
                d0 = pack2bf(acc[d][0].x, acc[d][1].x);
                d1 = pack2bf(acc[d][2].x, acc[d][3].x);
                d2 = pack2bf(acc[d][4].x, acc[d][5].x);
                d3 = pack2bf(acc[d][6].x, acc[d][7].x);
            } else {
                d0 = pack2bf(acc[d][0].y, acc[d][1].y);
                d1 = pack2bf(acc[d][2].y, acc[d][3].y);
                d2 = pack2bf(acc[d][4].y, acc[d][5].y);
                d3 = pack2bf(acc[d][6].y, acc[d][7].y);
            }
            *(uint4*)(ag + (h * 8 + i) * 8) = make_uint4(d0, d1, d2, d3);
        }
    }
    __syncthreads();   // the ONE barrier: both waves' aggA ready

    // ---- phase C: 16 pts x 32 o per wave; A from LDS, W from L1-hot global ----
    {
        int row = l & 15, q = l >> 4;
        int oA = w * 32 + row, oB = oA + 16;
        const unsigned short* arow = sm + (row >> 3) * REGW + 8 * PST
                                     + (row & 7) * AST + q * 8;
        const unsigned short* wrA = Wb + (size_t)oA * CM + q * 8;
        const unsigned short* wrB = Wb + (size_t)oB * CM + q * 8;
        // residual + bias (issued before MFMA loop, consumed after)
        float4 resA = *(const float4*)(feature + ((size_t)b * CC + oA) * NNN + n0 + q * 4);
        float4 resB = *(const float4*)(feature + ((size_t)b * CC + oB) * NNN + n0 + q * 4);
        float biasA = conv_b[oA], biasB = conv_b[oB];

        f32x4 dA = {0.f, 0.f, 0.f, 0.f};
        f32x4 dB = {0.f, 0.f, 0.f, 0.f};
        #pragma unroll
        for (int s = 0; s < 16; ++s) {
            bf16x8 af = *(const bf16x8*)(arow + s * 32);
            bf16x8 w0 = *(const bf16x8*)(wrA + s * 32);
            bf16x8 w1 = *(const bf16x8*)(wrB + s * 32);
            dA = __builtin_amdgcn_mfma_f32_16x16x32_bf16(af, w0, dA, 0, 0, 0);
            dB = __builtin_amdgcn_mfma_f32_16x16x32_bf16(af, w1, dB, 0, 0, 0);
        }
        float4 rA, rB;
        #pragma unroll
        for (int r = 0; r < 4; ++r) {
            float vA = dA[r] + biasA;
            vA = vA > 0.f ? vA : vA * 0.2f;
            ((float*)&rA)[r] = vA + ((const float*)&resA)[r];
            float vB = dB[r] + biasB;
            vB = vB > 0.f ? vB : vB * 0.2f;
            ((float*)&rB)[r] = vB + ((const float*)&resB)[r];
        }
        *(float4*)(out + ((size_t)b * OC + oA) * NNN + n0 + q * 4) = rA;
        *(float4*)(out + ((size_t)b * OC + oB) * NNN + n0 + q * 4) = rB;
    }
}

extern "C" void kernel_launch(void* const* d_in, const int* in_sizes, int n_in,
                              void* d_out, int out_size, void* d_ws, size_t ws_size,
                              hipStream_t stream) {
    const float* x        = (const float*)d_in[0];
    const float* feature  = (const float*)d_in[1];
    const int*   nidx     = (const int*)d_in[2];
    const float* kern     = (const float*)d_in[3];
    const float* conv_w   = (const float*)d_in[4];
    const float* conv_b   = (const float*)d_in[5];
    float* out = (float*)d_out;

    char* ws = (char*)d_ws;
    unsigned short* ftr  = (unsigned short*)ws;                      // 4 MB  (B,N,C) bf16
    unsigned short* Wb   = (unsigned short*)(ws + (4u << 20));       // 64 KB bf16 W [o][k]
    float*          proj = (float*)(ws + (4u << 20) + (64u << 10));  // 1 MB (B,N,M) f32

    prep_kernel<<<548, 256, 0, stream>>>(x, feature, kern, conv_w, ftr, Wb, proj);
    main_kernel<<<2048, 128, 0, stream>>>(nidx, proj, ftr, Wb, conv_b, feature, out);
}